// Round 3
// baseline (194.136 us; speedup 1.0000x reference)
//
#include <hip/hip_runtime.h>

#define WST 72   // f16 LDS row stride (144 B = 9*16: aligned, benign banks)
#define LOG2E 1.44269504f

typedef __attribute__((ext_vector_type(4))) float    f32x4;
typedef __attribute__((ext_vector_type(2))) float    f32x2;
typedef __attribute__((ext_vector_type(8))) _Float16 f16x8;
typedef __attribute__((ext_vector_type(4))) _Float16 f16x4;
typedef __attribute__((ext_vector_type(2))) _Float16 f16x2;
typedef __attribute__((ext_vector_type(2))) __fp16   fp16x2_raw;

union U8 { f16x8 v; f16x2 h[4]; };

__device__ __forceinline__ float rcp_f(float x) { return __builtin_amdgcn_rcpf(x); }
__device__ __forceinline__ float exp2_f(float x) { return __builtin_amdgcn_exp2f(x); }
__device__ __forceinline__ float fast_sigmoid(float x) {
    return rcp_f(1.0f + __expf(-x));
}
__device__ __forceinline__ float tanh_exp(float x) {
    return 1.0f - 2.0f * rcp_f(__expf(2.0f * x) + 1.0f);
}
__device__ __forceinline__ f16x2 pkrtz(float a, float b) {
    fp16x2_raw r = __builtin_amdgcn_cvt_pkrtz(a, b);
    return __builtin_bit_cast(f16x2, r);
}

// ---- weight staging: global f32 -> LDS f16 transposed (Wt[c*WST+k] = W[k][c]) ----
// 1024-thread versions: 4 elements/thread for a 64x64 array.
__device__ __forceinline__ void wload4(const float* __restrict__ W, int tid, float v[4]) {
#pragma unroll
    for (int i = 0; i < 4; ++i) v[i] = W[tid + i * 1024];
}
__device__ __forceinline__ void wstore4(_Float16* Wt, int tid, const float v[4], float scale) {
#pragma unroll
    for (int i = 0; i < 4; ++i) {
        int idx = tid + i * 1024;
        Wt[(idx & 63) * WST + (idx >> 6)] = (_Float16)(v[i] * scale);
    }
}

// one 16x16(x64) GEMM tile: A rows [arow-frag], B cols [bcol], K=64 via 2 MFMA
__device__ __forceinline__ f32x4 gemm1(const _Float16* Act, int arow, int qd,
                                       const _Float16* Wt, int bcol, f32x4 acc) {
    f16x8 a0 = *(const f16x8*)(Act + arow * WST + qd * 8);
    f16x8 a1 = *(const f16x8*)(Act + arow * WST + 32 + qd * 8);
    const _Float16* wr = Wt + bcol * WST + qd * 8;
    f16x8 b0 = *(const f16x8*)(wr);
    f16x8 b1 = *(const f16x8*)(wr + 32);
    acc = __builtin_amdgcn_mfma_f32_16x16x32_f16(a0, b0, acc, 0, 0, 0);
    acc = __builtin_amdgcn_mfma_f32_16x16x32_f16(a1, b1, acc, 0, 0, 0);
    return acc;
}

// ---------------------------------------------------------------------------
// fused_all: block = (n, j-half), 1024 threads = 16 waves (4 waves/SIMD for
// trans/VALU pipe overlap). 7-phase prep with 16-way tile parallelism, then
// binary all-pairs (8 i-rows per wave) with paired-rcp tanh, exp2-folded
// paired-rcp sigmoid gate, and the (1-2r) affine folded into scaled weights.
// ---------------------------------------------------------------------------
__global__ __launch_bounds__(1024) void fused_all_kernel(
    const float* __restrict__ x,
    const float* __restrict__ W_lin, const float* __restrict__ b_lin,
    const float* __restrict__ Wu1,  const float* __restrict__ bu1,
    const float* __restrict__ Wu2,  const float* __restrict__ bu2,
    const float* __restrict__ Wug1, const float* __restrict__ bug1,
    const float* __restrict__ Wug2, const float* __restrict__ bug2,
    const float* __restrict__ Wb1,  const float* __restrict__ bb1,
    const float* __restrict__ Wb2,  const float* __restrict__ bb2,
    const float* __restrict__ Wbg1, const float* __restrict__ bbg1,
    const float* __restrict__ Wbg2, const float* __restrict__ bbg2,
    float* __restrict__ out)
{
    // slot lifetimes:
    // S0: W_lin -> Wbg1Q -> Tu/Tg      S1: Wb1P -> Wug1 -> -2*Wb2
    // S2: x(f16) -> Wbg1P -> Wug2      S3: h(Ah) -> 2log2e*Wbg2
    // S4: Wb1Q -> Wu1                  S5: Wu2
    __shared__ __align__(16) char smem[114176];
    _Float16* S0 = (_Float16*)(smem);
    _Float16* S1 = (_Float16*)(smem + 9216);
    _Float16* S2 = (_Float16*)(smem + 18432);
    _Float16* S3 = (_Float16*)(smem + 27648);
    _Float16* S4 = (_Float16*)(smem + 36864);
    _Float16* S5 = (_Float16*)(smem + 46080);
    float*    EPm  = (float*)(smem + 55296);     // 32x68 f32 (8704 B)
    float*    EPgm = (float*)(smem + 64000);     // 32x68 f32 (8704 B)
    float*    EQb  = (float*)(smem + 72704);     // 64x64 f32 (16384 B) - live in loop
    float*    EQgb = (float*)(smem + 89088);     // 64x64 f32 (16384 B) - live in loop
    float*    um32 = (float*)(smem + 105472);    // 32x64 f32 (8192 B)
    float*    csum_m = (float*)(smem + 113664);  // 64 f32
    float*    csum_g = (float*)(smem + 113920);  // 64 f32
    float*    Red  = (float*)(smem);             // 65536 B alias S0..EPgm (loop-dead)

    int tid = threadIdx.x, w = tid >> 6, l = tid & 63;
    int qd = l >> 4, l16 = l & 15;
    int n = blockIdx.x >> 1, jsel = blockIdx.x & 1;

    // 64x64 output mapping: 16 tiles of 16x16
    int rw = w & 3, cw = w >> 2;
    int arow64 = rw * 16 + l16;
    int bcol64 = cw * 16 + l16;
    int crow64 = rw * 16 + qd * 4;

    // 32x64 output mapping: 8 tiles, used by wave group 0-7 / 8-15
    int w8 = w & 7;
    int rw2 = w8 & 1, cw2 = w8 >> 1;
    int lrow32 = rw2 * 16;               // local row base within the 32-row j-set
    int bcol32 = cw2 * 16 + l16;
    bool loW = (w < 8);                  // wave-uniform

    // ---- P0: stage x -> S2 (f16), W_lin -> S0 ----
    {
        float wv[4];
        wload4(W_lin, tid, wv);
        int e = tid * 4;
        f32x4 v = *(const f32x4*)(x + (size_t)n * 4096 + e);
        f16x4 p;
#pragma unroll
        for (int t = 0; t < 4; ++t) p[t] = (_Float16)v[t];
        *(f16x4*)(S2 + (e >> 6) * WST + (e & 63)) = p;
        wstore4(S0, tid, wv, 1.0f);
    }
    __syncthreads();

    // ---- P1: h = x@W_lin + b_lin -> S3 (16 tiles); stage Wb1P->S1, Wb1Q->S4 ----
    {
        float wa[4], wb[4];
        wload4(Wb1, tid, wa);
        wload4(Wb1 + 4096, tid, wb);
        float bv = b_lin[bcol64];
        f32x4 acc = (f32x4){bv, bv, bv, bv};
        acc = gemm1(S2, arow64, qd, S0, bcol64, acc);
#pragma unroll
        for (int r = 0; r < 4; ++r)
            S3[(crow64 + r) * WST + bcol64] = (_Float16)acc[r];
        wstore4(S1, tid, wa, 1.0f);
        wstore4(S4, tid, wb, 1.0f);
    }
    __syncthreads();

    // ---- P2: EQ = exp(2(h@Wb1Q)) -> EQb (16 tiles); stage Wbg1P->S2, Wbg1Q->S0 ----
    {
        float wa[4], wb[4];
        wload4(Wbg1, tid, wa);
        wload4(Wbg1 + 4096, tid, wb);
        f32x4 acc = (f32x4){0.f, 0.f, 0.f, 0.f};
        acc = gemm1(S3, arow64, qd, S4, bcol64, acc);
#pragma unroll
        for (int r = 0; r < 4; ++r)
            EQb[(crow64 + r) * 64 + bcol64] = __expf(2.0f * acc[r]);
        wstore4(S2, tid, wa, 1.0f);
        wstore4(S0, tid, wb, 1.0f);
    }
    __syncthreads();

    // ---- P3: loW: EP = exp(2(h@Wb1P+bb1)) -> EPm; hiW: EPg -> EPgm;
    //          stage Wu1->S4, Wu2->S5 ----
    {
        float wa[4], wb[4];
        wload4(Wu1, tid, wa);
        wload4(Wu2, tid, wb);
        const _Float16* Bw = loW ? S1 : S2;
        const float* b1 = loW ? bb1 : bbg1;
        float* dst = loW ? EPm : EPgm;
        float bv = b1[bcol32];
        f32x4 acc = (f32x4){bv, bv, bv, bv};
        acc = gemm1(S3, jsel * 32 + lrow32 + l16, qd, Bw, bcol32, acc);
#pragma unroll
        for (int r = 0; r < 4; ++r)
            dst[(lrow32 + qd * 4 + r) * 68 + bcol32] = __expf(2.0f * acc[r]);
        wstore4(S4, tid, wa, 1.0f);
        wstore4(S5, tid, wb, 1.0f);
    }
    __syncthreads();

    // ---- P4: EQg = exp(2(h@Wbg1Q)) -> EQgb (16 tiles); stage Wug1->S1, Wug2->S2 ----
    {
        float wa[4], wb[4];
        wload4(Wug1, tid, wa);
        wload4(Wug2, tid, wb);
        f32x4 acc = (f32x4){0.f, 0.f, 0.f, 0.f};
        acc = gemm1(S3, arow64, qd, S0, bcol64, acc);
#pragma unroll
        for (int r = 0; r < 4; ++r)
            EQgb[(crow64 + r) * 64 + bcol64] = __expf(2.0f * acc[r]);
        wstore4(S1, tid, wa, 1.0f);
        wstore4(S2, tid, wb, 1.0f);
    }
    __syncthreads();

    // ---- P5: loW: Tu = tanh(h@Wu1+bu1); hiW: Tg = tanh(h@Wug1+bug1) -> S0 ----
    {
        const _Float16* Bw = loW ? S4 : S1;
        const float* b1 = loW ? bu1 : bug1;
        _Float16* Tdst = loW ? S0 : (S0 + 2304);   // 32x72 f16 each
        float bv = b1[bcol32];
        f32x4 acc = (f32x4){bv, bv, bv, bv};
        acc = gemm1(S3, jsel * 32 + lrow32 + l16, qd, Bw, bcol32, acc);
#pragma unroll
        for (int r = 0; r < 4; ++r)
            Tdst[(lrow32 + qd * 4 + r) * WST + bcol32] = (_Float16)tanh_exp(acc[r]);
    }
    __syncthreads();

    // ---- P6: waves 0-7: U = Tu@Wu2+bu2, G = Tg@Wug2+bug2, um = U*sig(G) -> um32;
    //          waves 8-15: stage -2*Wb2 -> S1, 2log2e*Wbg2 -> S3, csum fold ----
    if (loW) {
        float bv = bu2[bcol32];
        f32x4 ua = (f32x4){bv, bv, bv, bv};
        ua = gemm1(S0, lrow32 + l16, qd, S5, bcol32, ua);
        bv = bug2[bcol32];
        f32x4 ga = (f32x4){bv, bv, bv, bv};
        ga = gemm1(S0 + 2304, lrow32 + l16, qd, S2, bcol32, ga);
#pragma unroll
        for (int r = 0; r < 4; ++r)
            um32[(lrow32 + qd * 4 + r) * 64 + bcol32] = ua[r] * fast_sigmoid(ga[r]);
    } else {
        int tid2 = tid - 512;
        float wm[8], wg[8];
#pragma unroll
        for (int i = 0; i < 8; ++i) {
            wm[i] = Wb2[tid2 + i * 512];
            wg[i] = Wbg2[tid2 + i * 512];
        }
        // csum fold: bim = bb2 - 0.5*sum(f16(-2W)); big = -log2e*bbg2 - 0.5*sum(f16(2log2e*W))
        if (w == 8) {
            float cs = 0.0f;
#pragma unroll 16
            for (int k = 0; k < 64; ++k)
                cs += (float)(_Float16)(-2.0f * Wb2[k * 64 + l]);
            csum_m[l] = bb2[l] - 0.5f * cs;
        }
        if (w == 9) {
            float cs = 0.0f;
#pragma unroll 16
            for (int k = 0; k < 64; ++k)
                cs += (float)(_Float16)(2.0f * LOG2E * Wbg2[k * 64 + l]);
            csum_g[l] = -LOG2E * bbg2[l] - 0.5f * cs;
        }
#pragma unroll
        for (int i = 0; i < 8; ++i) {
            int idx = tid2 + i * 512;
            int o = (idx & 63) * WST + (idx >> 6);
            S1[o] = (_Float16)(wm[i] * -2.0f);
            S3[o] = (_Float16)(wg[i] * (2.0f * LOG2E));
        }
    }
    __syncthreads();

    // =============== binary phase: 2 j-groups x 8 i-ranges (8 ii each) ===============
    int jgrp = w >> 3, iw = w & 7;

    f16x8 bwm[4][2], bwg[4][2];
#pragma unroll
    for (int cc = 0; cc < 4; ++cc)
#pragma unroll
        for (int kk = 0; kk < 2; ++kk) {
            bwm[cc][kk] = *(const f16x8*)(S1 + (cc * 16 + l16) * WST + kk * 32 + qd * 8);
            bwg[cc][kk] = *(const f16x8*)(S3 + (cc * 16 + l16) * WST + kk * 32 + qd * 8);
        }
    float bim[4], big[4];
#pragma unroll
    for (int cc = 0; cc < 4; ++cc) {
        bim[cc] = csum_m[cc * 16 + l16];
        big[cc] = csum_g[cc * 16 + l16];
    }

    const float* pr  = EPm  + (jgrp * 16 + l16) * 68;
    const float* pgr = EPgm + (jgrp * 16 + l16) * 68;
    f32x4 pm[4], pg[4];
    pm[0] = *(const f32x4*)(pr + qd * 8);
    pm[1] = *(const f32x4*)(pr + qd * 8 + 4);
    pm[2] = *(const f32x4*)(pr + 32 + qd * 8);
    pm[3] = *(const f32x4*)(pr + 32 + qd * 8 + 4);
    pg[0] = *(const f32x4*)(pgr + qd * 8);
    pg[1] = *(const f32x4*)(pgr + qd * 8 + 4);
    pg[2] = *(const f32x4*)(pgr + 32 + qd * 8);
    pg[3] = *(const f32x4*)(pgr + 32 + qd * 8 + 4);

    f32x4 bacc[4];
#pragma unroll
    for (int cc = 0; cc < 4; ++cc) bacc[cc] = (f32x4){0.f, 0.f, 0.f, 0.f};

    for (int ii = iw * 8; ii < iw * 8 + 8; ++ii) {
        const float* qm = EQb  + ii * 64;
        const float* qg = EQgb + ii * 64;
        U8 am[2], ag[2];
#pragma unroll
        for (int kk = 0; kk < 2; ++kk) {
            int cb = kk * 32 + qd * 8;
            f32x4 qa = *(const f32x4*)(qm + cb);
            f32x4 qb = *(const f32x4*)(qm + cb + 4);
            f32x4 ha = *(const f32x4*)(qg + cb);
            f32x4 hb = *(const f32x4*)(qg + cb + 4);
#pragma unroll
            for (int t = 0; t < 2; ++t) {
                // paired reciprocal: 1/a0,1/a1 from one rcp(a0*a1)
                float a0 = __builtin_fmaf(pm[kk*2][2*t],   qa[2*t],   1.0f);
                float a1 = __builtin_fmaf(pm[kk*2][2*t+1], qa[2*t+1], 1.0f);
                float ri = rcp_f(a0 * a1);
                am[kk].h[t]     = pkrtz(ri * a1, ri * a0);
                float b0f = __builtin_fmaf(pm[kk*2+1][2*t],   qb[2*t],   1.0f);
                float b1f = __builtin_fmaf(pm[kk*2+1][2*t+1], qb[2*t+1], 1.0f);
                float rj = rcp_f(b0f * b1f);
                am[kk].h[2 + t] = pkrtz(rj * b1f, rj * b0f);
                float c0 = __builtin_fmaf(pg[kk*2][2*t],   ha[2*t],   1.0f);
                float c1 = __builtin_fmaf(pg[kk*2][2*t+1], ha[2*t+1], 1.0f);
                float rk = rcp_f(c0 * c1);
                ag[kk].h[t]     = pkrtz(rk * c1, rk * c0);
                float d0 = __builtin_fmaf(pg[kk*2+1][2*t],   hb[2*t],   1.0f);
                float d1 = __builtin_fmaf(pg[kk*2+1][2*t+1], hb[2*t+1], 1.0f);
                float rl = rcp_f(d0 * d1);
                ag[kk].h[2 + t] = pkrtz(rl * d1, rl * d0);
            }
        }
#pragma unroll
        for (int cc = 0; cc < 4; ++cc) {
            f32x4 d = {bim[cc], bim[cc], bim[cc], bim[cc]};
            d = __builtin_amdgcn_mfma_f32_16x16x32_f16(am[0].v, bwm[cc][0], d, 0, 0, 0);
            d = __builtin_amdgcn_mfma_f32_16x16x32_f16(am[1].v, bwm[cc][1], d, 0, 0, 0);
            // e = -log2e * G (fold): sigmoid(G) = 1/(1 + exp2(e))
            f32x4 e = {big[cc], big[cc], big[cc], big[cc]};
            e = __builtin_amdgcn_mfma_f32_16x16x32_f16(ag[0].v, bwg[cc][0], e, 0, 0, 0);
            e = __builtin_amdgcn_mfma_f32_16x16x32_f16(ag[1].v, bwg[cc][1], e, 0, 0, 0);
            // paired-rcp sigmoid accumulate
            float v0 = exp2_f(e[0]), v1 = exp2_f(e[1]);
            float u0 = 1.0f + v0, u1 = 1.0f + v1;
            float r01 = rcp_f(u0 * u1);
            bacc[cc][0] = __builtin_fmaf(d[0] * u1, r01, bacc[cc][0]);
            bacc[cc][1] = __builtin_fmaf(d[1] * u0, r01, bacc[cc][1]);
            float v2 = exp2_f(e[2]), v3 = exp2_f(e[3]);
            float u2 = 1.0f + v2, u3 = 1.0f + v3;
            float r23 = rcp_f(u2 * u3);
            bacc[cc][2] = __builtin_fmaf(d[2] * u3, r23, bacc[cc][2]);
            bacc[cc][3] = __builtin_fmaf(d[3] * u2, r23, bacc[cc][3]);
        }
    }

    __syncthreads();   // all waves done reading S*/EP* before Red overwrites
#pragma unroll
    for (int cc = 0; cc < 4; ++cc)
#pragma unroll
        for (int r = 0; r < 4; ++r)
            Red[(jgrp * 8 + iw) * 1024 + (qd * 4 + r) * 64 + cc * 16 + l16] = bacc[cc][r];
    __syncthreads();

    // reduce 8 i-ranges, add unary, write out (1024 thr x 2 floats = 32x64)
    {
        int e = tid * 2;
        int lr = e >> 6, col = e & 63;
        int g = lr >> 4, rr = lr & 15;
        f32x2 s = {0.f, 0.f};
#pragma unroll
        for (int p = 0; p < 8; ++p)
            s += *(const f32x2*)(Red + (g * 8 + p) * 1024 + rr * 64 + col);
        f32x2 u = *(const f32x2*)(um32 + lr * 64 + col);
        f32x2 o;
        o[0] = u[0] + s[0] * (1.0f / 63.0f);
        o[1] = u[1] + s[1] * (1.0f / 63.0f);
        *(f32x2*)(out + (size_t)n * 4096 + (size_t)(jsel * 32 + lr) * 64 + col) = o;
    }
}

extern "C" void kernel_launch(void* const* d_in, const int* in_sizes, int n_in,
                              void* d_out, int out_size, void* d_ws, size_t ws_size,
                              hipStream_t stream)
{
    (void)in_sizes; (void)n_in; (void)out_size; (void)d_ws; (void)ws_size;
    const float* x     = (const float*)d_in[0];
    const float* W_lin = (const float*)d_in[1];
    const float* b_lin = (const float*)d_in[2];
    const float* Wu1   = (const float*)d_in[3];
    const float* bu1   = (const float*)d_in[4];
    const float* Wu2   = (const float*)d_in[5];
    const float* bu2   = (const float*)d_in[6];
    const float* Wug1  = (const float*)d_in[7];
    const float* bug1  = (const float*)d_in[8];
    const float* Wug2  = (const float*)d_in[9];
    const float* bug2  = (const float*)d_in[10];
    const float* Wb1   = (const float*)d_in[11];
    const float* bb1   = (const float*)d_in[12];
    const float* Wb2   = (const float*)d_in[13];
    const float* bb2   = (const float*)d_in[14];
    const float* Wbg1  = (const float*)d_in[15];
    const float* bbg1  = (const float*)d_in[16];
    const float* Wbg2  = (const float*)d_in[17];
    const float* bbg2  = (const float*)d_in[18];

    hipLaunchKernelGGL(fused_all_kernel, dim3(256), dim3(1024), 0, stream,
        x, W_lin, b_lin, Wu1, bu1, Wu2, bu2, Wug1, bug1, Wug2, bug2,
        Wb1, bb1, Wb2, bb2, Wbg1, bbg1, Wbg2, bbg2,
        (float*)d_out);
}

// Round 4
// 117.376 us; speedup vs baseline: 1.6540x; 1.6540x over previous
//
#include <hip/hip_runtime.h>

#define WST 72   // f16 LDS row stride (144 B = 9*16: aligned, benign banks)
#define LOG2E 1.44269504f

typedef __attribute__((ext_vector_type(4))) float    f32x4;
typedef __attribute__((ext_vector_type(2))) float    f32x2;
typedef __attribute__((ext_vector_type(8))) _Float16 f16x8;
typedef __attribute__((ext_vector_type(2))) _Float16 f16x2;
typedef __attribute__((ext_vector_type(2))) __fp16   fp16x2_raw;

union U8 { f16x8 v; f16x2 h[4]; };

__device__ __forceinline__ float rcp_f(float x) { return __builtin_amdgcn_rcpf(x); }
__device__ __forceinline__ float exp2_f(float x) { return __builtin_amdgcn_exp2f(x); }
__device__ __forceinline__ float fast_sigmoid(float x) {
    return rcp_f(1.0f + __expf(-x));
}
__device__ __forceinline__ float tanh_exp(float x) {
    return 1.0f - 2.0f * rcp_f(__expf(2.0f * x) + 1.0f);
}
__device__ __forceinline__ f16x2 pkrtz(float a, float b) {
    fp16x2_raw r = __builtin_amdgcn_cvt_pkrtz(a, b);
    return __builtin_bit_cast(f16x2, r);
}

// ---- weight staging: global f32 -> LDS f16 transposed (Wt[c*WST+k] = W[k][c]) ----
__device__ __forceinline__ void wload8(const float* __restrict__ W, int tid, float v[8]) {
#pragma unroll
    for (int i = 0; i < 8; ++i) v[i] = W[tid + i * 512];
}
__device__ __forceinline__ void wstore8(_Float16* Wt, int tid, const float v[8], float scale) {
#pragma unroll
    for (int i = 0; i < 8; ++i) {
        int idx = tid + i * 512;
        Wt[(idx & 63) * WST + (idx >> 6)] = (_Float16)(v[i] * scale);
    }
}
__device__ __forceinline__ void wload16(const float* __restrict__ W, int t256, float v[16]) {
#pragma unroll
    for (int i = 0; i < 16; ++i) v[i] = W[t256 + i * 256];
}

// one 16x16(x64) strip of a 64x64x64 GEMM: wave covers rows [arow..), cols
// [colb, colb+16) and [colb+16, colb+32). acc pre-loaded with bias.
__device__ __forceinline__ void gemm2(const _Float16* Act, int arow, int qd,
                                      const _Float16* Wt, int colb,
                                      f32x4 acc[2]) {
    f16x8 a0 = *(const f16x8*)(Act + arow * WST + qd * 8);
    f16x8 a1 = *(const f16x8*)(Act + arow * WST + 32 + qd * 8);
#pragma unroll
    for (int cc = 0; cc < 2; ++cc) {
        const _Float16* wr = Wt + (colb + cc * 16) * WST + qd * 8;
        f16x8 b0 = *(const f16x8*)(wr);
        f16x8 b1 = *(const f16x8*)(wr + 32);
        acc[cc] = __builtin_amdgcn_mfma_f32_16x16x32_f16(a0, b0, acc[cc], 0, 0, 0);
        acc[cc] = __builtin_amdgcn_mfma_f32_16x16x32_f16(a1, b1, acc[cc], 0, 0, 0);
    }
}

// ---------------------------------------------------------------------------
// fused_all: block = (n, j-half), 512 thr / 8 waves (VGPR cap 256 - binary
// loop needs ~160, so 2 waves/SIMD is mandatory; R3 proved 4 waves spills).
// 4-phase prep: P0 stage x/W_lin; P1 h-gemm + stage ALL 6 first-layer weight
// halves; P2 mega-phase (EQ,EQg,EP/EPg,Tu/Tg - 4 independent gemm chains per
// wave, one barrier); P3 U/G/um + binary-weight staging. Then binary all-pairs
// with paired-rcp tanh and exp2-folded paired-rcp sigmoid gate.
// ---------------------------------------------------------------------------
__global__ __launch_bounds__(512, 2) void fused_all_kernel(
    const float* __restrict__ x,
    const float* __restrict__ W_lin, const float* __restrict__ b_lin,
    const float* __restrict__ Wu1,  const float* __restrict__ bu1,
    const float* __restrict__ Wu2,  const float* __restrict__ bu2,
    const float* __restrict__ Wug1, const float* __restrict__ bug1,
    const float* __restrict__ Wug2, const float* __restrict__ bug2,
    const float* __restrict__ Wb1,  const float* __restrict__ bb1,
    const float* __restrict__ Wb2,  const float* __restrict__ bb2,
    const float* __restrict__ Wbg1, const float* __restrict__ bbg1,
    const float* __restrict__ Wbg2, const float* __restrict__ bbg2,
    float* __restrict__ out)
{
    __shared__ __align__(16) char smem[152576];
    _Float16* WLs = (_Float16*)(smem);             // W_lin(T) -> Tu(+0)/Tg(+2304 elems)
    _Float16* SX  = (_Float16*)(smem + 9216);      // x(f16) -> Wu2(T)
    _Float16* SH  = (_Float16*)(smem + 18432);     // h (64x72 f16)
    _Float16* W1  = (_Float16*)(smem + 27648);     // Wb1P -> -2*Wb2
    _Float16* W2  = (_Float16*)(smem + 36864);     // Wb1Q -> 2log2e*Wbg2
    _Float16* W3  = (_Float16*)(smem + 46080);     // Wbg1P
    _Float16* W4  = (_Float16*)(smem + 55296);     // Wbg1Q
    _Float16* W5  = (_Float16*)(smem + 64512);     // Wu1
    _Float16* W6  = (_Float16*)(smem + 73728);     // Wug1
    _Float16* W7  = (_Float16*)(smem + 82944);     // Wug2(T)
    float*    EPm  = (float*)(smem + 92160);       // 32x68 f32 (8704 B)
    float*    EPgm = (float*)(smem + 100864);      // 32x68 f32
    float*    EQb  = (float*)(smem + 109568);      // 64x64 f32 (16384 B)
    float*    EQgb = (float*)(smem + 125952);      // 64x64 f32
    float*    um32 = (float*)(smem + 142336);      // 32x64 f32 (8192 B)
    float*    csP  = (float*)(smem + 150528);      // [8][64] f32: q0-3 m, q4-7 g partials
    float*    Red  = (float*)(smem);               // 32768 B alias WLs..W1 (binary-dead)

    int tid = threadIdx.x, w = tid >> 6, l = tid & 63;
    int qd = l >> 4, l16 = l & 15;
    int n = blockIdx.x >> 1, jsel = blockIdx.x & 1;

    // full 64x64 gemm mapping: 4 row-quarters x 2 col-halves
    int rw = w & 3, ch = w >> 2;
    int arow = rw * 16 + l16;
    int colb = ch * 32 + l16;
    int crow = rw * 16 + qd * 4;

    // 32x64 strip mapping (P2 own-strip / P3): s = w&3
    int s = w & 3;
    int lr16 = (s & 1) * 16;
    int cb32 = (s >> 1) * 32;
    bool loW = (w < 4);                  // wave-uniform

    f32x4 acc[2];

    // ---- P0: stage x -> SX (f16), W_lin -> WLs ----
#pragma unroll
    for (int i = 0; i < 4; ++i) {
        int e = tid * 2 + i * 1024;
        f32x2 v = *(const f32x2*)(x + (size_t)n * 4096 + e);
        f16x2 p; p[0] = (_Float16)v[0]; p[1] = (_Float16)v[1];
        *(f16x2*)(SX + (e >> 6) * WST + (e & 63)) = p;
    }
    {
        float wv[8];
        wload8(W_lin, tid, wv);
        wstore8(WLs, tid, wv, 1.0f);
    }
    __syncthreads();

    // ---- P1: h = x@W_lin + b_lin -> SH; stage all 6 first-layer halves ----
    {
        float wv0[8], wv1[8], wv2[8], wv3[8], wv4[8], wv5[8];
        wload8(Wb1, tid, wv0);
        wload8(Wb1 + 4096, tid, wv1);
        wload8(Wbg1, tid, wv2);
        wload8(Wbg1 + 4096, tid, wv3);
        wload8(Wu1, tid, wv4);
        wload8(Wug1, tid, wv5);
#pragma unroll
        for (int cc = 0; cc < 2; ++cc) {
            float bv = b_lin[colb + cc * 16];
            acc[cc] = (f32x4){bv, bv, bv, bv};
        }
        gemm2(SX, arow, qd, WLs, colb, acc);
#pragma unroll
        for (int cc = 0; cc < 2; ++cc)
#pragma unroll
            for (int r = 0; r < 4; ++r)
                SH[(crow + r) * WST + colb + cc * 16] = (_Float16)acc[cc][r];
        wstore8(W1, tid, wv0, 1.0f);
        wstore8(W2, tid, wv1, 1.0f);
        wstore8(W3, tid, wv2, 1.0f);
        wstore8(W4, tid, wv3, 1.0f);
        wstore8(W5, tid, wv4, 1.0f);
        wstore8(W6, tid, wv5, 1.0f);
    }
    __syncthreads();

    // ---- P2 (mega): 4 independent gemm chains per wave, one barrier.
    //   all waves: EQ strip (h@Wb1Q), EQg strip (h@Wbg1Q) over full 64 rows
    //   waves 0-3: EP strip s (own j-rows), Tu strip s
    //   waves 4-7: EPg strip s, Tg strip s
    //   + stage Wu2 -> SX, Wug2 -> W7 (from regs; x/W_lin dead) ----
    {
        float wu2v[8], wug2v[8];
        wload8(Wu2, tid, wu2v);
        wload8(Wug2, tid, wug2v);

        // EQ = exp(2*(h@Wb1Q)), no bias
        acc[0] = (f32x4){0.f, 0.f, 0.f, 0.f};
        acc[1] = (f32x4){0.f, 0.f, 0.f, 0.f};
        gemm2(SH, arow, qd, W2, colb, acc);
#pragma unroll
        for (int cc = 0; cc < 2; ++cc)
#pragma unroll
            for (int r = 0; r < 4; ++r)
                EQb[(crow + r) * 64 + colb + cc * 16] = __expf(2.0f * acc[cc][r]);

        // EQg = exp(2*(h@Wbg1Q)), no bias
        f32x4 accg[2];
        accg[0] = (f32x4){0.f, 0.f, 0.f, 0.f};
        accg[1] = (f32x4){0.f, 0.f, 0.f, 0.f};
        gemm2(SH, arow, qd, W4, colb, accg);
#pragma unroll
        for (int cc = 0; cc < 2; ++cc)
#pragma unroll
            for (int r = 0; r < 4; ++r)
                EQgb[(crow + r) * 64 + colb + cc * 16] = __expf(2.0f * accg[cc][r]);

        // own-strip work on rows jsel*32 + [lr16, lr16+16)
        const _Float16* Wp = loW ? W1 : W3;      // Wb1P : Wbg1P
        const _Float16* Wt = loW ? W5 : W6;      // Wu1  : Wug1
        const float* bp = loW ? bb1 : bbg1;
        const float* bt = loW ? bu1 : bug1;
        float* EPdst = loW ? EPm : EPgm;
        _Float16* Tdst = loW ? WLs : (WLs + 2304);  // Tu / Tg (32x72 each)

        f32x4 accp[2];
#pragma unroll
        for (int cc = 0; cc < 2; ++cc) {
            float bv = bp[cb32 + cc * 16 + l16];
            accp[cc] = (f32x4){bv, bv, bv, bv};
        }
        gemm2(SH, jsel * 32 + lr16 + l16, qd, Wp, cb32 + l16, accp);
#pragma unroll
        for (int cc = 0; cc < 2; ++cc)
#pragma unroll
            for (int r = 0; r < 4; ++r)
                EPdst[(lr16 + qd * 4 + r) * 68 + cb32 + cc * 16 + l16] =
                    __expf(2.0f * accp[cc][r]);

        f32x4 acct[2];
#pragma unroll
        for (int cc = 0; cc < 2; ++cc) {
            float bv = bt[cb32 + cc * 16 + l16];
            acct[cc] = (f32x4){bv, bv, bv, bv};
        }
        gemm2(SH, jsel * 32 + lr16 + l16, qd, Wt, cb32 + l16, acct);
#pragma unroll
        for (int cc = 0; cc < 2; ++cc)
#pragma unroll
            for (int r = 0; r < 4; ++r)
                Tdst[(lr16 + qd * 4 + r) * WST + cb32 + cc * 16 + l16] =
                    (_Float16)tanh_exp(acct[cc][r]);

        wstore8(SX, tid, wu2v, 1.0f);
        wstore8(W7, tid, wug2v, 1.0f);
    }
    __syncthreads();

    // ---- P3: waves 0-3: U = Tu@Wu2+bu2, G = Tg@Wug2+bug2, um = U*sig(G);
    //          waves 4-7: stage -2*Wb2 -> W1, 2log2e*Wbg2 -> W2 + csum partials ----
    if (loW) {
        f32x4 ua[2], ga[2];
#pragma unroll
        for (int cc = 0; cc < 2; ++cc) {
            float bv = bu2[cb32 + cc * 16 + l16];
            ua[cc] = (f32x4){bv, bv, bv, bv};
        }
        gemm2(WLs, lr16 + l16, qd, SX, cb32 + l16, ua);
#pragma unroll
        for (int cc = 0; cc < 2; ++cc) {
            float bv = bug2[cb32 + cc * 16 + l16];
            ga[cc] = (f32x4){bv, bv, bv, bv};
        }
        gemm2(WLs + 2304, lr16 + l16, qd, W7, cb32 + l16, ga);
#pragma unroll
        for (int cc = 0; cc < 2; ++cc)
#pragma unroll
            for (int r = 0; r < 4; ++r)
                um32[(lr16 + qd * 4 + r) * 64 + cb32 + cc * 16 + l16] =
                    ua[cc][r] * fast_sigmoid(ga[cc][r]);
    } else {
        int tid2 = tid - 256;                    // 0..255
        float wm[16], wg[16];
        wload16(Wb2, tid2, wm);
        wload16(Wbg2, tid2, wg);
        float csm = 0.0f, csg = 0.0f;
#pragma unroll
        for (int i = 0; i < 16; ++i) {
            int idx = tid2 + i * 256;
            int o = (idx & 63) * WST + (idx >> 6);
            _Float16 a = (_Float16)(wm[i] * -2.0f);
            _Float16 b = (_Float16)(wg[i] * (2.0f * LOG2E));
            W1[o] = a;
            W2[o] = b;
            csm += (float)a;
            csg += (float)b;
        }
        int q = tid2 >> 6, c = tid2 & 63;        // 4 partials per col per matrix
        csP[q * 64 + c] = csm;
        csP[256 + q * 64 + c] = csg;
    }
    __syncthreads();

    // =============== binary phase: 2 j-groups x 4 i-ranges (16 ii each) ===============
    int jgrp = w >> 2, iw = w & 3;

    // B fragments from staged weights
    f16x8 bwm[4][2], bwg[4][2];
#pragma unroll
    for (int cc = 0; cc < 4; ++cc)
#pragma unroll
        for (int kk = 0; kk < 2; ++kk) {
            bwm[cc][kk] = *(const f16x8*)(W1 + (cc * 16 + l16) * WST + kk * 32 + qd * 8);
            bwg[cc][kk] = *(const f16x8*)(W2 + (cc * 16 + l16) * WST + kk * 32 + qd * 8);
        }
    float bim[4], big[4];
#pragma unroll
    for (int cc = 0; cc < 4; ++cc) {
        int c = cc * 16 + l16;
        bim[cc] = bb2[c] -
            0.5f * (csP[c] + csP[64 + c] + csP[128 + c] + csP[192 + c]);
        big[cc] = -LOG2E * bbg2[c] -
            0.5f * (csP[256 + c] + csP[320 + c] + csP[384 + c] + csP[448 + c]);
    }

    // P fragments (loop-invariant, register-resident)
    const float* pr  = EPm  + (jgrp * 16 + l16) * 68;
    const float* pgr = EPgm + (jgrp * 16 + l16) * 68;
    f32x4 pm[4], pg[4];
    pm[0] = *(const f32x4*)(pr + qd * 8);
    pm[1] = *(const f32x4*)(pr + qd * 8 + 4);
    pm[2] = *(const f32x4*)(pr + 32 + qd * 8);
    pm[3] = *(const f32x4*)(pr + 32 + qd * 8 + 4);
    pg[0] = *(const f32x4*)(pgr + qd * 8);
    pg[1] = *(const f32x4*)(pgr + qd * 8 + 4);
    pg[2] = *(const f32x4*)(pgr + 32 + qd * 8);
    pg[3] = *(const f32x4*)(pgr + 32 + qd * 8 + 4);

    f32x4 bacc[4];
#pragma unroll
    for (int cc = 0; cc < 4; ++cc) bacc[cc] = (f32x4){0.f, 0.f, 0.f, 0.f};

    for (int ii = iw * 16; ii < iw * 16 + 16; ++ii) {
        const float* qm = EQb  + ii * 64;
        const float* qg = EQgb + ii * 64;
        U8 am[2], ag[2];
#pragma unroll
        for (int kk = 0; kk < 2; ++kk) {
            int cb = kk * 32 + qd * 8;
            f32x4 qa = *(const f32x4*)(qm + cb);
            f32x4 qb = *(const f32x4*)(qm + cb + 4);
            f32x4 ha = *(const f32x4*)(qg + cb);
            f32x4 hb = *(const f32x4*)(qg + cb + 4);
#pragma unroll
            for (int t = 0; t < 2; ++t) {
                // paired reciprocal: 1/a0,1/a1 from one rcp(a0*a1)
                float a0 = __builtin_fmaf(pm[kk*2][2*t],   qa[2*t],   1.0f);
                float a1 = __builtin_fmaf(pm[kk*2][2*t+1], qa[2*t+1], 1.0f);
                float ri = rcp_f(a0 * a1);
                am[kk].h[t]     = pkrtz(ri * a1, ri * a0);
                float b0f = __builtin_fmaf(pm[kk*2+1][2*t],   qb[2*t],   1.0f);
                float b1f = __builtin_fmaf(pm[kk*2+1][2*t+1], qb[2*t+1], 1.0f);
                float rj = rcp_f(b0f * b1f);
                am[kk].h[2 + t] = pkrtz(rj * b1f, rj * b0f);
                float c0 = __builtin_fmaf(pg[kk*2][2*t],   ha[2*t],   1.0f);
                float c1 = __builtin_fmaf(pg[kk*2][2*t+1], ha[2*t+1], 1.0f);
                float rk = rcp_f(c0 * c1);
                ag[kk].h[t]     = pkrtz(rk * c1, rk * c0);
                float d0 = __builtin_fmaf(pg[kk*2+1][2*t],   hb[2*t],   1.0f);
                float d1 = __builtin_fmaf(pg[kk*2+1][2*t+1], hb[2*t+1], 1.0f);
                float rl = rcp_f(d0 * d1);
                ag[kk].h[2 + t] = pkrtz(rl * d1, rl * d0);
            }
        }
#pragma unroll
        for (int cc = 0; cc < 4; ++cc) {
            f32x4 d = {bim[cc], bim[cc], bim[cc], bim[cc]};
            d = __builtin_amdgcn_mfma_f32_16x16x32_f16(am[0].v, bwm[cc][0], d, 0, 0, 0);
            d = __builtin_amdgcn_mfma_f32_16x16x32_f16(am[1].v, bwm[cc][1], d, 0, 0, 0);
            // e = -log2e*G (fold): sigmoid(G) = 1/(1+exp2(e))
            f32x4 e = {big[cc], big[cc], big[cc], big[cc]};
            e = __builtin_amdgcn_mfma_f32_16x16x32_f16(ag[0].v, bwg[cc][0], e, 0, 0, 0);
            e = __builtin_amdgcn_mfma_f32_16x16x32_f16(ag[1].v, bwg[cc][1], e, 0, 0, 0);
            // paired-rcp sigmoid accumulate
            float v0 = exp2_f(e[0]), v1 = exp2_f(e[1]);
            float u0 = 1.0f + v0, u1 = 1.0f + v1;
            float r01 = rcp_f(u0 * u1);
            bacc[cc][0] = __builtin_fmaf(d[0] * u1, r01, bacc[cc][0]);
            bacc[cc][1] = __builtin_fmaf(d[1] * u0, r01, bacc[cc][1]);
            float v2 = exp2_f(e[2]), v3 = exp2_f(e[3]);
            float u2 = 1.0f + v2, u3 = 1.0f + v3;
            float r23 = rcp_f(u2 * u3);
            bacc[cc][2] = __builtin_fmaf(d[2] * u3, r23, bacc[cc][2]);
            bacc[cc][3] = __builtin_fmaf(d[3] * u2, r23, bacc[cc][3]);
        }
    }

    __syncthreads();   // all waves done with W1/W2 frags + EQ/EP reads
#pragma unroll
    for (int cc = 0; cc < 4; ++cc)
#pragma unroll
        for (int r = 0; r < 4; ++r)
            Red[(jgrp * 4 + iw) * 1024 + (qd * 4 + r) * 64 + cc * 16 + l16] = bacc[cc][r];
    __syncthreads();

    // reduce 4 i-ranges, add unary, write out
    {
        int e = tid * 4;                 // 512 thr x 4 = 2048 = 32x64
        int lr = e >> 6, col = e & 63;
        int g = lr >> 4, rr = lr & 15;
        f32x4 sv = {0.f, 0.f, 0.f, 0.f};
#pragma unroll
        for (int p = 0; p < 4; ++p)
            sv += *(const f32x4*)(Red + (g * 4 + p) * 1024 + rr * 64 + col);
        f32x4 u = *(const f32x4*)(um32 + lr * 64 + col);
        f32x4 o;
#pragma unroll
        for (int t = 0; t < 4; ++t)
            o[t] = u[t] + sv[t] * (1.0f / 63.0f);
        *(f32x4*)(out + (size_t)n * 4096 + (size_t)(jsel * 32 + lr) * 64 + col) = o;
    }
}

extern "C" void kernel_launch(void* const* d_in, const int* in_sizes, int n_in,
                              void* d_out, int out_size, void* d_ws, size_t ws_size,
                              hipStream_t stream)
{
    (void)in_sizes; (void)n_in; (void)out_size; (void)d_ws; (void)ws_size;
    const float* x     = (const float*)d_in[0];
    const float* W_lin = (const float*)d_in[1];
    const float* b_lin = (const float*)d_in[2];
    const float* Wu1   = (const float*)d_in[3];
    const float* bu1   = (const float*)d_in[4];
    const float* Wu2   = (const float*)d_in[5];
    const float* bu2   = (const float*)d_in[6];
    const float* Wug1  = (const float*)d_in[7];
    const float* bug1  = (const float*)d_in[8];
    const float* Wug2  = (const float*)d_in[9];
    const float* bug2  = (const float*)d_in[10];
    const float* Wb1   = (const float*)d_in[11];
    const float* bb1   = (const float*)d_in[12];
    const float* Wb2   = (const float*)d_in[13];
    const float* bb2   = (const float*)d_in[14];
    const float* Wbg1  = (const float*)d_in[15];
    const float* bbg1  = (const float*)d_in[16];
    const float* Wbg2  = (const float*)d_in[17];
    const float* bbg2  = (const float*)d_in[18];

    hipLaunchKernelGGL(fused_all_kernel, dim3(256), dim3(512), 0, stream,
        x, W_lin, b_lin, Wu1, bu1, Wu2, bu2, Wug1, bug1, Wug2, bug2,
        Wb1, bb1, Wb2, bb2, Wbg1, bbg1, Wbg2, bbg2,
        (float*)d_out);
}